// Round 1
// baseline (4320.526 us; speedup 1.0000x reference)
//
#include <hip/hip_runtime.h>

// LightGCN forward on MI355X.
// Inputs: user_emb[100000,64] f32, item_emb[50000,64] f32,
//         edge_row[6.4M] i32, edge_col[6.4M] i32, edge_val[6.4M] f32,
//         users[4096] i32, items[4096] i32
// Output: gamma[4096] f32.

#define N_USERS  100000
#define N_ITEMS  50000
#define N_TOTAL  150000          // N_USERS + N_ITEMS
#define D        64
#define NNZ      6400000
#define BATCH    4096
#define NELEM    (N_TOTAL * D)   // 9,600,000

// acc = cur = concat(user_emb, item_emb); nxt = 0
__global__ void lgcn_init(const float* __restrict__ user_emb,
                          const float* __restrict__ item_emb,
                          float* __restrict__ acc,
                          float* __restrict__ cur,
                          float* __restrict__ nxt) {
    int i = blockIdx.x * blockDim.x + threadIdx.x;
    if (i < NELEM) {
        float v = (i < N_USERS * D) ? user_emb[i] : item_emb[i - N_USERS * D];
        acc[i] = v;
        cur[i] = v;
        nxt[i] = 0.0f;
    }
}

// Edge-parallel SpMM: one wave (64 lanes) per edge, lane = dim.
// nxt[row, d] += val * cur[col, d]
__global__ void lgcn_spmm(const int*   __restrict__ rows,
                          const int*   __restrict__ cols,
                          const float* __restrict__ vals,
                          const float* __restrict__ cur,
                          float*       __restrict__ nxt) {
    long long t = (long long)blockIdx.x * blockDim.x + threadIdx.x;
    int e = (int)(t >> 6);
    int d = (int)(t & 63);
    if (e < NNZ) {
        int   r = rows[e];
        int   c = cols[e];
        float v = vals[e];
        float x = cur[c * D + d];                 // coalesced 256B wave-load
        unsafeAtomicAdd(&nxt[r * D + d], v * x);  // HW global_atomic_add_f32
    }
}

// acc += src; optionally zero a buffer for the next layer's target.
__global__ void lgcn_accum(float* __restrict__ acc,
                           const float* __restrict__ src,
                           float* __restrict__ to_zero) {
    int i = blockIdx.x * blockDim.x + threadIdx.x;
    if (i < NELEM) {
        acc[i] += src[i];
        if (to_zero) to_zero[i] = 0.0f;
    }
}

// gamma[b] = dot(acc[users[b]], acc[N_USERS+items[b]]) / 16
// (both operands carry the /4 layer-mean)
__global__ void lgcn_dot(const float* __restrict__ acc,
                         const int* __restrict__ users,
                         const int* __restrict__ items,
                         float* __restrict__ out) {
    int t = blockIdx.x * blockDim.x + threadIdx.x;
    int b = t >> 6;
    int d = t & 63;
    if (b < BATCH) {
        int u  = users[b];
        int it = items[b];
        float p = acc[u * D + d] * acc[(N_USERS + it) * D + d];
        #pragma unroll
        for (int off = 32; off; off >>= 1) p += __shfl_down(p, off, 64);
        if (d == 0) out[b] = p * (1.0f / 16.0f);
    }
}

extern "C" void kernel_launch(void* const* d_in, const int* in_sizes, int n_in,
                              void* d_out, int out_size, void* d_ws, size_t ws_size,
                              hipStream_t stream) {
    const float* user_emb = (const float*)d_in[0];
    const float* item_emb = (const float*)d_in[1];
    const int*   edge_row = (const int*)d_in[2];
    const int*   edge_col = (const int*)d_in[3];
    const float* edge_val = (const float*)d_in[4];
    const int*   users    = (const int*)d_in[5];
    const int*   items    = (const int*)d_in[6];
    float*       out      = (float*)d_out;

    float* acc = (float*)d_ws;            // [NELEM]
    float* A   = acc + NELEM;             // [NELEM] ping
    float* B   = A + NELEM;               // [NELEM] pong

    const int TPB = 256;
    int init_blocks = (NELEM + TPB - 1) / TPB;
    long long spmm_threads = (long long)NNZ * 64;
    int spmm_blocks = (int)((spmm_threads + TPB - 1) / TPB);
    int dot_blocks = (BATCH * 64 + TPB - 1) / TPB;

    // acc = A = E0 ; B = 0
    lgcn_init<<<init_blocks, TPB, 0, stream>>>(user_emb, item_emb, acc, A, B);

    // layer 1: A -> B ; acc += B ; zero A
    lgcn_spmm<<<spmm_blocks, TPB, 0, stream>>>(edge_row, edge_col, edge_val, A, B);
    lgcn_accum<<<init_blocks, TPB, 0, stream>>>(acc, B, A);

    // layer 2: B -> A ; acc += A ; zero B
    lgcn_spmm<<<spmm_blocks, TPB, 0, stream>>>(edge_row, edge_col, edge_val, B, A);
    lgcn_accum<<<init_blocks, TPB, 0, stream>>>(acc, A, B);

    // layer 3: A -> B ; acc += B
    lgcn_spmm<<<spmm_blocks, TPB, 0, stream>>>(edge_row, edge_col, edge_val, A, B);
    lgcn_accum<<<init_blocks, TPB, 0, stream>>>(acc, B, nullptr);

    // gamma
    lgcn_dot<<<dot_blocks, TPB, 0, stream>>>(acc, users, items, out);
}

// Round 2
// 1582.325 us; speedup vs baseline: 2.7305x; 2.7305x over previous
//
#include <hip/hip_runtime.h>

// LightGCN forward on MI355X — round 2: CSR-gather SpMM (no f32 atomics).
// Round-1 evidence: WRITE_SIZE == NNZ*256B exactly -> device-scope f32 atomics
// write through to the memory side (per-XCD L2 non-coherent); atomic-bound.
// Fix: per-call CSR build (int atomics only, 1/edge), then gather-form SpMM.

#define N_USERS  100000
#define N_ITEMS  50000
#define N_TOTAL  150000          // N_USERS + N_ITEMS
#define D        64
#define NNZ      6400000
#define BATCH    4096
#define NELEM    (N_TOTAL * D)   // 9,600,000
#define SCAN_B   ((N_TOTAL + 255) / 256)   // 586 blocks of 256

// ---------- init: acc = cur = concat(user,item); zero counts ----------
__global__ void lgcn_init_csr(const float* __restrict__ user_emb,
                              const float* __restrict__ item_emb,
                              float* __restrict__ acc,
                              float* __restrict__ cur,
                              int*   __restrict__ counts) {
    int i = blockIdx.x * blockDim.x + threadIdx.x;
    if (i < NELEM) {
        float v = (i < N_USERS * D) ? user_emb[i] : item_emb[i - N_USERS * D];
        acc[i] = v;
        cur[i] = v;
    }
    if (i < N_TOTAL) counts[i] = 0;
}

// ---------- CSR build ----------
__global__ void lgcn_hist(const int* __restrict__ rows, int* __restrict__ counts) {
    int e = blockIdx.x * blockDim.x + threadIdx.x;
    if (e < NNZ) atomicAdd(&counts[rows[e]], 1);
}

// per-256-block sums of counts
__global__ void lgcn_scan_reduce(const int* __restrict__ counts,
                                 int* __restrict__ blockSums) {
    __shared__ int s[256];
    int tid = threadIdx.x;
    int i = blockIdx.x * 256 + tid;
    s[tid] = (i < N_TOTAL) ? counts[i] : 0;
    __syncthreads();
    for (int off = 128; off; off >>= 1) {
        if (tid < off) s[tid] += s[tid + off];
        __syncthreads();
    }
    if (tid == 0) blockSums[blockIdx.x] = s[0];
}

// exclusive scan of blockSums (<=1024 elems) in one block
__global__ void lgcn_scan_mid(int* __restrict__ blockSums) {
    __shared__ int s[1024];
    int tid = threadIdx.x;
    int v = (tid < SCAN_B) ? blockSums[tid] : 0;
    s[tid] = v;
    __syncthreads();
    for (int off = 1; off < 1024; off <<= 1) {
        int t = (tid >= off) ? s[tid - off] : 0;
        __syncthreads();
        s[tid] += t;
        __syncthreads();
    }
    if (tid < SCAN_B) blockSums[tid] = s[tid] - v;   // exclusive
}

// exclusive scan within block + block offset -> row_ptr, cursor
__global__ void lgcn_scan_final(const int* __restrict__ counts,
                                const int* __restrict__ blockSums,
                                int* __restrict__ row_ptr,
                                int* __restrict__ cursor) {
    __shared__ int s[256];
    int tid = threadIdx.x;
    int i = blockIdx.x * 256 + tid;
    int v = (i < N_TOTAL) ? counts[i] : 0;
    s[tid] = v;
    __syncthreads();
    for (int off = 1; off < 256; off <<= 1) {
        int t = (tid >= off) ? s[tid - off] : 0;
        __syncthreads();
        s[tid] += t;
        __syncthreads();
    }
    if (i < N_TOTAL) {
        int excl = s[tid] - v + blockSums[blockIdx.x];
        row_ptr[i] = excl;
        cursor[i]  = excl;
    }
}

// scatter edges into CSR order: pairs[pos] = (col, val)
__global__ void lgcn_scatter(const int*   __restrict__ rows,
                             const int*   __restrict__ cols,
                             const float* __restrict__ vals,
                             int*         __restrict__ cursor,
                             int2*        __restrict__ pairs) {
    int e = blockIdx.x * blockDim.x + threadIdx.x;
    if (e < NNZ) {
        int r = rows[e];
        int pos = atomicAdd(&cursor[r], 1);
        int2 p;
        p.x = cols[e];
        p.y = __float_as_int(vals[e]);
        pairs[pos] = p;
    }
}

// ---------- gather SpMM: one wave per row, lane = dim ----------
// nxt[r,:] = sum_e val_e * cur[col_e,:];  acc[r,:] += nxt[r,:]
__global__ void lgcn_spmm_csr(const int2* __restrict__ pairs,
                              const int*  __restrict__ row_ptr,
                              const int*  __restrict__ counts,
                              const float* __restrict__ cur,
                              float* __restrict__ nxt,
                              float* __restrict__ acc) {
    int t = blockIdx.x * blockDim.x + threadIdx.x;
    int r = t >> 6;
    int lane = t & 63;
    if (r >= N_TOTAL) return;
    int start = row_ptr[r];
    int cnt   = counts[r];
    float sum0 = 0.f, sum1 = 0.f;
    for (int base = 0; base < cnt; base += 64) {
        int idx = base + lane;
        int2 p = {0, 0};
        if (idx < cnt) p = pairs[start + idx];     // coalesced dwordx2
        int m = cnt - base; if (m > 64) m = 64;
        int j = 0;
        for (; j + 4 <= m; j += 4) {               // 4 outstanding gathers
            int   c0 = __shfl(p.x, j,     64);
            int   c1 = __shfl(p.x, j + 1, 64);
            int   c2 = __shfl(p.x, j + 2, 64);
            int   c3 = __shfl(p.x, j + 3, 64);
            float v0 = __int_as_float(__shfl(p.y, j,     64));
            float v1 = __int_as_float(__shfl(p.y, j + 1, 64));
            float v2 = __int_as_float(__shfl(p.y, j + 2, 64));
            float v3 = __int_as_float(__shfl(p.y, j + 3, 64));
            float x0 = cur[c0 * D + lane];
            float x1 = cur[c1 * D + lane];
            float x2 = cur[c2 * D + lane];
            float x3 = cur[c3 * D + lane];
            sum0 += v0 * x0;
            sum1 += v1 * x1;
            sum0 += v2 * x2;
            sum1 += v3 * x3;
        }
        for (; j < m; j++) {
            int   c = __shfl(p.x, j, 64);
            float v = __int_as_float(__shfl(p.y, j, 64));
            sum0 += v * cur[c * D + lane];
        }
    }
    float sum = sum0 + sum1;
    int o = r * D + lane;
    nxt[o] = sum;            // input to next layer (fully overwritten)
    acc[o] += sum;
}

// ---------- epilogue dot ----------
__global__ void lgcn_dot(const float* __restrict__ acc,
                         const int* __restrict__ users,
                         const int* __restrict__ items,
                         float* __restrict__ out) {
    int t = blockIdx.x * blockDim.x + threadIdx.x;
    int b = t >> 6;
    int d = t & 63;
    if (b < BATCH) {
        int u  = users[b];
        int it = items[b];
        float p = acc[u * D + d] * acc[(N_USERS + it) * D + d];
        #pragma unroll
        for (int off = 32; off; off >>= 1) p += __shfl_down(p, off, 64);
        if (d == 0) out[b] = p * (1.0f / 16.0f);
    }
}

// ---------- round-1 fallback (atomic scatter) if ws too small ----------
__global__ void lgcn_init_fb(const float* __restrict__ user_emb,
                             const float* __restrict__ item_emb,
                             float* __restrict__ acc,
                             float* __restrict__ cur,
                             float* __restrict__ nxt) {
    int i = blockIdx.x * blockDim.x + threadIdx.x;
    if (i < NELEM) {
        float v = (i < N_USERS * D) ? user_emb[i] : item_emb[i - N_USERS * D];
        acc[i] = v; cur[i] = v; nxt[i] = 0.0f;
    }
}
__global__ void lgcn_spmm_fb(const int* __restrict__ rows,
                             const int* __restrict__ cols,
                             const float* __restrict__ vals,
                             const float* __restrict__ cur,
                             float* __restrict__ nxt) {
    long long t = (long long)blockIdx.x * blockDim.x + threadIdx.x;
    int e = (int)(t >> 6);
    int d = (int)(t & 63);
    if (e < NNZ) {
        float x = cur[cols[e] * D + d];
        unsafeAtomicAdd(&nxt[rows[e] * D + d], vals[e] * x);
    }
}
__global__ void lgcn_accum_fb(float* __restrict__ acc,
                              const float* __restrict__ src,
                              float* __restrict__ to_zero) {
    int i = blockIdx.x * blockDim.x + threadIdx.x;
    if (i < NELEM) {
        acc[i] += src[i];
        if (to_zero) to_zero[i] = 0.0f;
    }
}

extern "C" void kernel_launch(void* const* d_in, const int* in_sizes, int n_in,
                              void* d_out, int out_size, void* d_ws, size_t ws_size,
                              hipStream_t stream) {
    const float* user_emb = (const float*)d_in[0];
    const float* item_emb = (const float*)d_in[1];
    const int*   edge_row = (const int*)d_in[2];
    const int*   edge_col = (const int*)d_in[3];
    const float* edge_val = (const float*)d_in[4];
    const int*   users    = (const int*)d_in[5];
    const int*   items    = (const int*)d_in[6];
    float*       out      = (float*)d_out;

    const int TPB = 256;
    int init_blocks = (NELEM + TPB - 1) / TPB;
    int edge_blocks = (NNZ + TPB - 1) / TPB;
    int spmm_blocks = (N_TOTAL * 64 + TPB - 1) / TPB;   // wave per row
    int dot_blocks  = (BATCH * 64 + TPB - 1) / TPB;

    // workspace layout
    float* acc = (float*)d_ws;                 // NELEM
    float* A   = acc + NELEM;                  // NELEM
    float* B   = A + NELEM;                    // NELEM
    int2*  pairs    = (int2*)(B + NELEM);      // NNZ int2
    int*   row_ptr  = (int*)(pairs + NNZ);     // N_TOTAL
    int*   counts   = row_ptr + N_TOTAL;       // N_TOTAL
    int*   cursor   = counts + N_TOTAL;        // N_TOTAL
    int*   blockSums = cursor + N_TOTAL;       // 1024
    size_t req = (size_t)(blockSums + 1024 - (int*)d_ws) * 4;

    if (ws_size < req) {
        // fallback: round-1 atomic path (needs only 3*NELEM floats)
        long long st = (long long)NNZ * 64;
        int sb = (int)((st + TPB - 1) / TPB);
        lgcn_init_fb<<<init_blocks, TPB, 0, stream>>>(user_emb, item_emb, acc, A, B);
        lgcn_spmm_fb<<<sb, TPB, 0, stream>>>(edge_row, edge_col, edge_val, A, B);
        lgcn_accum_fb<<<init_blocks, TPB, 0, stream>>>(acc, B, A);
        lgcn_spmm_fb<<<sb, TPB, 0, stream>>>(edge_row, edge_col, edge_val, B, A);
        lgcn_accum_fb<<<init_blocks, TPB, 0, stream>>>(acc, A, B);
        lgcn_spmm_fb<<<sb, TPB, 0, stream>>>(edge_row, edge_col, edge_val, A, B);
        lgcn_accum_fb<<<init_blocks, TPB, 0, stream>>>(acc, B, nullptr);
        lgcn_dot<<<dot_blocks, TPB, 0, stream>>>(acc, users, items, out);
        return;
    }

    // init embeddings + zero histogram
    lgcn_init_csr<<<init_blocks, TPB, 0, stream>>>(user_emb, item_emb, acc, A, counts);

    // CSR build: hist -> scan -> scatter
    lgcn_hist<<<edge_blocks, TPB, 0, stream>>>(edge_row, counts);
    lgcn_scan_reduce<<<SCAN_B, 256, 0, stream>>>(counts, blockSums);
    lgcn_scan_mid<<<1, 1024, 0, stream>>>(blockSums);
    lgcn_scan_final<<<SCAN_B, 256, 0, stream>>>(counts, blockSums, row_ptr, cursor);
    lgcn_scatter<<<edge_blocks, TPB, 0, stream>>>(edge_row, edge_col, edge_val, cursor, pairs);

    // 3 propagation layers, acc += fused
    lgcn_spmm_csr<<<spmm_blocks, TPB, 0, stream>>>(pairs, row_ptr, counts, A, B, acc);
    lgcn_spmm_csr<<<spmm_blocks, TPB, 0, stream>>>(pairs, row_ptr, counts, B, A, acc);
    lgcn_spmm_csr<<<spmm_blocks, TPB, 0, stream>>>(pairs, row_ptr, counts, A, B, acc);

    // gamma
    lgcn_dot<<<dot_blocks, TPB, 0, stream>>>(acc, users, items, out);
}